// Round 8
// baseline (443.033 us; speedup 1.0000x reference)
//
#include <hip/hip_runtime.h>

// B=8, R=8, N=1024, D_IN=D_OUT=256, all fp32 in/out.
// prep_w : Wt[r][e][d] = bf16(W[r][d][e])      (ws[40MB:41MB))
// stage 1: supP = bf16(x@W + bias), PACKED in gemm B-fragment order (ws[0:34MB))
// stage 2: out[b,m,e] = relu(sum_r adj[b,r,m,:] @ sup)  fused over r.
//
// R13: four structures all ~150-165us; invariant = BOTH operands LDS-round-tripped behind a
// per-stage barrier (LDS ops/stage > MFMA cycles; FETCH 160MB < adj 256MB shows L3 serving
// -> not BW-bound, staging-throttled at ~1TB/s). We OWN sup's layout: support now stores it
// pre-packed in B-fragment order: supP[((b8+r)*16+nsl)*2+et)*4+wv][jj][kh][lane][8] -- gemm
// loads B-frags DIRECT from global, 1KB dense/inst, register banks 3-deep, no LDS/barrier.
// Only adj stages via LDS (input layout fixed): 16-lane-dense f32x4 chunks (256B/inst, vs
// R7's 32B-stride half-dense), 4 bufs, 1 barrier/stage, ONE combined vmcnt(10)/stage.
// LDS 27KB; sup[b]=4MB L2-resident (bid&7=b); e-tile 128 (adj 2x via L2/L3, proven absorbed).

#define Rr 8
#define Nn 1024
#define Dd 256
#define AP 104   // adj LDS pitch (shorts): 52 dw = 20 mod 32, proven frag-read class
#define EP2 132  // gemm epilogue f32 bounce pitch
#define EPS 72   // support epilogue bf16 bounce pitch

typedef __attribute__((ext_vector_type(8))) short short8;
typedef __attribute__((ext_vector_type(4))) short short4s;
typedef __attribute__((ext_vector_type(4))) float f32x4;

__device__ __forceinline__ short f2bf(float f) {
    unsigned u = __builtin_bit_cast(unsigned, f);
    u += 0x7fffu + ((u >> 16) & 1u);   // RNE
    return (short)(u >> 16);
}

__device__ __forceinline__ short8 cvt8(f32x4 lo, f32x4 hi) {
    short8 t;
    t[0] = f2bf(lo[0]); t[1] = f2bf(lo[1]); t[2] = f2bf(lo[2]); t[3] = f2bf(lo[3]);
    t[4] = f2bf(hi[0]); t[5] = f2bf(hi[1]); t[6] = f2bf(hi[2]); t[7] = f2bf(hi[3]);
    return t;
}

__device__ __forceinline__ short4s cvt4(f32x4 v) {
    short4s t;
    t[0] = f2bf(v[0]); t[1] = f2bf(v[1]); t[2] = f2bf(v[2]); t[3] = f2bf(v[3]);
    return t;
}

// ---------------- prep: Wt[r][e][d] bf16 <- W[r][d][e] f32 ----------------
__global__ void prep_w_kernel(const float* __restrict__ W, short* __restrict__ Wt) {
    __shared__ short T[64][72];
    const int tid = threadIdx.x;
    const int et = blockIdx.x, dt = blockIdx.y, r = blockIdx.z;
    const float* Wr = W + ((size_t)r * Dd + dt * 64) * Dd + et * 64;
    #pragma unroll
    for (int i = 0; i < 4; ++i) {
        int idx = tid + i * 256;
        int d_l = idx >> 4;
        int e4  = (idx & 15) * 4;
        f32x4 v = *(const f32x4*)(Wr + d_l * Dd + e4);
        T[e4 + 0][d_l] = f2bf(v[0]);
        T[e4 + 1][d_l] = f2bf(v[1]);
        T[e4 + 2][d_l] = f2bf(v[2]);
        T[e4 + 3][d_l] = f2bf(v[3]);
    }
    __syncthreads();
    short* o = Wt + ((size_t)r * Dd + et * 64) * Dd + dt * 64;
    #pragma unroll
    for (int i = 0; i < 2; ++i) {
        int idx = tid + i * 256;
        *(short8*)(o + (idx >> 3) * Dd + (idx & 7) * 8) = *(const short8*)&T[idx >> 3][(idx & 7) * 8];
    }
}

// ---------------- Stage 1: supP = bf16(Wt @ x^T + bias), packed B-frag order ----------------
// 64e x 64n tile, K=256 in 4 stages of 64. grid 4096: d&7=b -> x[b] XCD-local.
// Pack: element (e_g, n = n_t*64 + kh*32 + quad*8 + c) stored at
// supP[(((((b*8+r)*16+n_t)*2+et)*4+wv)*2+jj)*2+kh][quad*16+l16][c],
// et=e_g>>7, wv=(e_g>>5)&3, jj=(e_g>>4)&1, l16=e_g&15 -- 1KB blocks, dense per gemm-wave-inst.
__global__ __launch_bounds__(256, 3) void support_kernel(
        const float* __restrict__ x, const short* __restrict__ Wt,
        const float* __restrict__ bias, short* __restrict__ supP) {
    __shared__ short As[2][64 * AP];   // Wt rows [e][k]
    __shared__ short Bs[2][64 * AP];   // x  rows [n][k] (cvt bf16)

    const int tid = threadIdx.x;
    const int wave = tid >> 6, lane = tid & 63;
    const int quad = lane >> 4, l16 = lane & 15;
    const int lrow = tid >> 3, lc = tid & 7;
    const int d = blockIdx.x;
    const int b = d & 7, rest = d >> 3;
    const int e_t = rest & 3, n_t = (rest >> 2) & 15, r = rest >> 6;
    const int e0 = e_t * 64, n0 = n_t * 64;
    const int we = wave & 1, wn = wave >> 1;

    const short* wp = Wt + ((size_t)r * Dd + e0) * Dd;
    const float* xb = x + ((size_t)b * Nn + n0) * Dd;

    short8 Wa0[2], Wa1[2];
    f32x4  Xv0[4], Xv1[4];

#define SGLOAD(WW, XX, t) do { int d0_ = (t) * 64;                              \
        _Pragma("unroll")                                                       \
        for (int p_ = 0; p_ < 2; ++p_) { int row_ = lrow + p_ * 32;             \
            WW[p_] = *(const short8*)(wp + (size_t)row_ * Dd + d0_ + lc * 8);   \
            const float* px_ = xb + (size_t)row_ * Dd + d0_ + lc * 8;           \
            XX[2 * p_]     = *(const f32x4*)px_;                                \
            XX[2 * p_ + 1] = *(const f32x4*)(px_ + 4); } } while (0)

#define SWRITE(BW, WW, XX) do {                                                 \
        _Pragma("unroll")                                                       \
        for (int p_ = 0; p_ < 2; ++p_) { int row_ = lrow + p_ * 32;             \
            *(short8*)&As[BW][row_ * AP + lc * 8] = WW[p_];                     \
            *(short8*)&Bs[BW][row_ * AP + lc * 8] = cvt8(XX[2 * p_], XX[2 * p_ + 1]); } } while (0)

#define SCOMP(BR) do {                                                          \
        _Pragma("unroll")                                                       \
        for (int kk_ = 0; kk_ < 2; ++kk_) { short8 af_[2], bf_[2];              \
            _Pragma("unroll")                                                   \
            for (int i_ = 0; i_ < 2; ++i_)                                      \
                af_[i_] = *(const short8*)&As[BR][(we * 32 + i_ * 16 + l16) * AP + kk_ * 32 + quad * 8]; \
            _Pragma("unroll")                                                   \
            for (int j_ = 0; j_ < 2; ++j_)                                      \
                bf_[j_] = *(const short8*)&Bs[BR][(wn * 32 + j_ * 16 + l16) * AP + kk_ * 32 + quad * 8]; \
            __builtin_amdgcn_s_setprio(1);                                      \
            _Pragma("unroll")                                                   \
            for (int i_ = 0; i_ < 2; ++i_)                                      \
                _Pragma("unroll")                                               \
                for (int j_ = 0; j_ < 2; ++j_)                                  \
                    acc[i_][j_] = __builtin_amdgcn_mfma_f32_16x16x32_bf16(af_[i_], bf_[j_], acc[i_][j_], 0, 0, 0); \
            __builtin_amdgcn_s_setprio(0); } } while (0)

#define SITER(t, VM, BW, WW, XX, BR) do {                                       \
        asm volatile("s_waitcnt vmcnt(" #VM ")" ::: "memory");                  \
        asm volatile("s_waitcnt lgkmcnt(0)" ::: "memory");                      \
        __builtin_amdgcn_s_barrier();                                           \
        asm volatile("" ::: "memory");                                          \
        SWRITE(BW, WW, XX);                                                     \
        if ((t) + 3 < 4) SGLOAD(WW, XX, (t) + 3);                               \
        SCOMP(BR); } while (0)

    f32x4 acc[2][2] = {};
    SGLOAD(Wa0, Xv0, 0);
    SGLOAD(Wa1, Xv1, 1);
    asm volatile("s_waitcnt vmcnt(6)" ::: "memory");
    SWRITE(0, Wa0, Xv0);
    SGLOAD(Wa0, Xv0, 2);
    SITER(0, 6, 1, Wa1, Xv1, 0);
    SITER(1, 6, 0, Wa0, Xv0, 1);
    SITER(2, 0, 1, Wa1, Xv1, 0);
    // final stage 3: no write, no load
    asm volatile("s_waitcnt lgkmcnt(0)" ::: "memory");
    __builtin_amdgcn_s_barrier();
    asm volatile("" ::: "memory");
    SCOMP(1);
#undef SGLOAD
#undef SWRITE
#undef SCOMP
#undef SITER

    // epilogue: bias + bf16 via LDS bounce, then packed 16B stores (256B-dense segments).
    __syncthreads();
    short* E = &As[0][0];   // 64 x EPS shorts = 9216 B, fits
    #pragma unroll
    for (int i = 0; i < 2; ++i)
        #pragma unroll
        for (int reg = 0; reg < 4; ++reg) {
            int e_l = we * 32 + i * 16 + quad * 4 + reg;
            float bv = bias[r * Dd + e0 + e_l];
            #pragma unroll
            for (int j = 0; j < 2; ++j)
                E[e_l * EPS + wn * 32 + j * 16 + l16] = f2bf(acc[i][j][reg] + bv);
        }
    __syncthreads();
    #pragma unroll
    for (int p = 0; p < 2; ++p) {
        int chunk = tid + p * 256;           // chunk = n8*64 + e_l
        int e_l = chunk & 63, n8 = chunk >> 6;
        int e_g = e0 + e_l;
        int pet = e_g >> 7, pwv = (e_g >> 5) & 3, pj = (e_g >> 4) & 1, pl = e_g & 15;
        int kh = n8 >> 2, qd = n8 & 3;
        size_t off = ((((((size_t)((b * Rr + r) * 16 + n_t) * 2 + pet) * 4 + pwv) * 2 + pj) * 2 + kh) * 64
                      + (qd * 16 + pl)) * 8;
        *(short8*)(supP + off) = *(const short8*)&E[e_l * EPS + n8 * 8];
    }
}

// ---------------- Stage 2: out = relu(sum_r adj @ sup), r fused into K ----------------
// block 256 = 4 waves; out tile 32m x 128e; wave wv: e = et*128 + wv*32 + [0,32).
// K = 8192 in 128 stages of 64 (stage t: r=t>>4, n0=(t&15)*64).
// adj via LDS (4 bufs, 1 barrier/stage); sup B-frags DIRECT from global (packed), 3-deep regs.
__global__ __launch_bounds__(256, 3) void gcn_gemm_kernel(
        const float* __restrict__ adj, const short* __restrict__ supP,
        float* __restrict__ out) {
    __shared__ short AsL[4][32 * AP];   // adj [m][k] bf16, 4 buffers (26.6 KB)

    const int tid = threadIdx.x;
    const int wv = tid >> 6, lane = tid & 63;
    const int quad = lane >> 4, l16 = lane & 15;
    const int d = blockIdx.x;                 // 512: b = d&7 -> XCD-local batch
    const int b = d & 7, z = d >> 3;
    const int et = z & 1, m0 = (z >> 1) * 32;
    const int arow = tid >> 4, ac4 = (tid & 15) * 4;   // adj chunk: 16 lanes x 16B = 256B dense

    f32x4  Aa0[2], Aa1[2];
    short8 Sv0[4], Sv1[4], Sv2[4], Sv3[4];
    f32x4  acc[2][2] = {};

#define GADJ(AA, t) do { int r_ = (t) >> 4, n0_ = ((t) & 15) * 64;              \
        const float* ap_ = adj + ((size_t)((b * Rr + r_) * Nn + m0)) * Nn + n0_; \
        AA[0] = *(const f32x4*)(ap_ + (size_t)arow * Nn + ac4);                 \
        AA[1] = *(const f32x4*)(ap_ + (size_t)(arow + 16) * Nn + ac4); } while (0)

#define GSUP(SS, t) do { int r_ = (t) >> 4, ns_ = (t) & 15;                     \
        const short* sp_ = supP + ((((size_t)(b * Rr + r_) * 16 + ns_) * 2 + et) * 4 + wv) * 2048 + lane * 8; \
        SS[0] = *(const short8*)(sp_);                                          \
        SS[1] = *(const short8*)(sp_ + 512);                                    \
        SS[2] = *(const short8*)(sp_ + 1024);                                   \
        SS[3] = *(const short8*)(sp_ + 1536); } while (0)

#define GWRITE(BW, AA) do {                                                     \
        *(short4s*)&AsL[BW][arow * AP + ac4] = cvt4(AA[0]);                     \
        *(short4s*)&AsL[BW][(arow + 16) * AP + ac4] = cvt4(AA[1]); } while (0)

#define GCOMP(SS, BR) do { short8 af_[4];                                       \
        _Pragma("unroll")                                                       \
        for (int i_ = 0; i_ < 2; ++i_)                                          \
            _Pragma("unroll")                                                   \
            for (int kh_ = 0; kh_ < 2; ++kh_)                                   \
                af_[i_ * 2 + kh_] = *(const short8*)&AsL[BR][(i_ * 16 + l16) * AP + kh_ * 32 + quad * 8]; \
        asm volatile("s_waitcnt lgkmcnt(0)" ::: "memory");                      \
        __builtin_amdgcn_sched_barrier(0);                                      \
        __builtin_amdgcn_s_setprio(1);                                          \
        _Pragma("unroll")                                                       \
        for (int kh_ = 0; kh_ < 2; ++kh_)                                       \
            _Pragma("unroll")                                                   \
            for (int i_ = 0; i_ < 2; ++i_)                                      \
                _Pragma("unroll")                                               \
                for (int j_ = 0; j_ < 2; ++j_)                                  \
                    acc[i_][j_] = __builtin_amdgcn_mfma_f32_16x16x32_bf16(af_[i_ * 2 + kh_], SS[j_ * 2 + kh_], acc[i_][j_], 0, 0, 0); \
        __builtin_amdgcn_s_setprio(0); } while (0)

// per stage t: ONE vmcnt wait (drains sup(t)+adj(t+1)), GWRITE(t+1), issue t+3, compute t, barrier.
#define GITER(t, VM, SR, SW, AW, BW, BR, DOI, DOW) do {                         \
        asm volatile("s_waitcnt vmcnt(" #VM ")" ::: "memory");                  \
        if (DOW) GWRITE(BW, AW);                                                \
        if (DOI) { GADJ(AW, (t) + 3); GSUP(SW, (t) + 3); }                      \
        GCOMP(SR, BR);                                                          \
        __builtin_amdgcn_s_barrier();                                           \
        asm volatile("" ::: "memory"); } while (0)

    // prologue: issue order per stage = [adj(2), sup(4)] -> steady queue 16, wait 10.
    GADJ(Aa0, 0); GSUP(Sv0, 0);
    GADJ(Aa1, 1); GSUP(Sv1, 1);
    asm volatile("s_waitcnt vmcnt(10)" ::: "memory");
    GWRITE(0, Aa0);
    GADJ(Aa0, 2); GSUP(Sv2, 2);
    asm volatile("s_waitcnt lgkmcnt(0)" ::: "memory");
    __builtin_amdgcn_s_barrier();
    asm volatile("" ::: "memory");

    for (int t0 = 0; t0 < 124; t0 += 4) {
        GITER(t0 + 0, 10, Sv0, Sv3, Aa1, 1, 0, 1, 1);
        GITER(t0 + 1, 10, Sv1, Sv0, Aa0, 2, 1, 1, 1);
        GITER(t0 + 2, 10, Sv2, Sv1, Aa1, 3, 2, 1, 1);
        GITER(t0 + 3, 10, Sv3, Sv2, Aa0, 0, 3, 1, 1);
    }
    GITER(124, 10, Sv0, Sv3, Aa1, 1, 0, 1, 1);   // last issue (t=127)
    GITER(125, 10, Sv1, Sv0, Aa0, 2, 1, 0, 1);
    GITER(126, 4,  Sv2, Sv1, Aa1, 3, 2, 0, 1);
    GITER(127, 0,  Sv3, Sv2, Aa0, 0, 3, 0, 0);
#undef GADJ
#undef GSUP
#undef GWRITE
#undef GCOMP
#undef GITER

    // epilogue: ReLU via f32 LDS bounce (16.9KB, fits bufs 0-2; buf3 reads already barriered).
    float* E = (float*)&AsL[0][0];
    #pragma unroll
    for (int i = 0; i < 2; ++i)
        #pragma unroll
        for (int j = 0; j < 2; ++j)
            #pragma unroll
            for (int reg = 0; reg < 4; ++reg)
                E[(i * 16 + quad * 4 + reg) * EP2 + wv * 32 + j * 16 + l16] =
                    fmaxf(acc[i][j][reg], 0.f);
    __syncthreads();
    float* ob = out + ((size_t)(b * Nn + m0)) * Dd + et * 128;
    #pragma unroll
    for (int k = 0; k < 4; ++k) {
        int row = tid >> 3, c = (tid & 7) * 16 + k * 4;
        *(f32x4*)(ob + (size_t)row * Dd + c) = *(const f32x4*)&E[row * EP2 + c];
    }
}

extern "C" void kernel_launch(void* const* d_in, const int* in_sizes, int n_in,
                              void* d_out, int out_size, void* d_ws, size_t ws_size,
                              hipStream_t stream) {
    const float* x    = (const float*)d_in[0];
    const float* adj  = (const float*)d_in[1];
    const float* W    = (const float*)d_in[2];
    const float* bias = (const float*)d_in[3];
    float* out = (float*)d_out;
    short* supP = (short*)d_ws;                          // ws[0:34MB), packed B-frag order
    short* Wt   = (short*)((char*)d_ws + (40u << 20));   // ws[40MB:41MB)

    prep_w_kernel<<<dim3(4, 4, 8), 256, 0, stream>>>(W, Wt);
    support_kernel<<<4096, 256, 0, stream>>>(x, Wt, bias, supP);
    gcn_gemm_kernel<<<512, 256, 0, stream>>>(adj, supP, out);
}